// Round 1
// baseline (120.144 us; speedup 1.0000x reference)
//
#include <hip/hip_runtime.h>

// Reference collapses algebraically:
//   V = ones  =>  V@Wk+bk is one row vector uk[c] = colsum(Wk)[c] + bk[c], same for all (b,l,o).
//   Attention scores are independent of the softmax axis (i)  =>  phi/psi/theta == 1/64 uniform.
//   phi @ relu(V@Wk+bk) == relu(uk)  (identical rows, row-sum-1 weights).
//   M[b,l,o,c] = sum_{k=1..4} relu(colsum(Wk)[c] + bk[c])  -- constant over (b,l,o).
// X and all a*/b*/c* attention parameters do not affect the output.

constexpr int D        = 128;
constexpr int NPOS     = 8 * 12 * 64;        // B*L*O = 6144 output rows
constexpr int N4       = NPOS * (D / 4);     // 196608 float4 stores (3 MB)
constexpr int NBLOCKS  = 64;
constexpr int NTHREADS = 256;

__global__ __launch_bounds__(NTHREADS)
void spatial_attn_const_kernel(const float* __restrict__ W1, const float* __restrict__ b1,
                               const float* __restrict__ W2, const float* __restrict__ b2,
                               const float* __restrict__ W3, const float* __restrict__ b3,
                               const float* __restrict__ W4, const float* __restrict__ b4,
                               float4* __restrict__ out) {
    __shared__ float sm[D];
    const int t = threadIdx.x;

    // Phase 1: threads 0..127 compute m[c] = sum_k relu(colsum(Wk)[c] + bk[c]).
    // Column-c access: for fixed r, consecutive threads read consecutive addresses
    // (coalesced). 4 * 128 * 128 floats = 256 KB per block, L2-resident after block 0.
    if (t < D) {
        const float* Ws[4] = {W1, W2, W3, W4};
        const float* bs[4] = {b1, b2, b3, b4};
        float total = 0.0f;
        for (int k = 0; k < 4; ++k) {
            float s = bs[k][t];
            const float* __restrict__ W = Ws[k];
            #pragma unroll 8
            for (int r = 0; r < D; ++r) {
                s += W[r * D + t];
            }
            total += fmaxf(s, 0.0f);
        }
        sm[t] = total;
    }
    __syncthreads();

    // Phase 2: broadcast-store the constant row. Row length = 128 floats = 32 float4.
    // Grid stride (16384) is a multiple of 32, so each thread's channel group is fixed.
    const float4 v = reinterpret_cast<const float4*>(sm)[t & 31];
    for (int i = blockIdx.x * NTHREADS + t; i < N4; i += NBLOCKS * NTHREADS) {
        out[i] = v;   // 12 iterations per thread, fully coalesced 16 B stores
    }
}

extern "C" void kernel_launch(void* const* d_in, const int* in_sizes, int n_in,
                              void* d_out, int out_size, void* d_ws, size_t ws_size,
                              hipStream_t stream) {
    // setup_inputs() dict order:
    //  0: X
    //  1..6  : aW1, ab1, aW2, ab2, aw3, ab3
    //  7..12 : bW1, bb1, bW2, bb2, bw3, bb3
    // 13..18 : cW1, cb1, cW2, cb2, cw3, cb3
    // 19..26 : W1, b1, W2, b2, W3, b3, W4, b4
    const float* W1 = (const float*)d_in[19];
    const float* b1 = (const float*)d_in[20];
    const float* W2 = (const float*)d_in[21];
    const float* b2 = (const float*)d_in[22];
    const float* W3 = (const float*)d_in[23];
    const float* b3 = (const float*)d_in[24];
    const float* W4 = (const float*)d_in[25];
    const float* b4 = (const float*)d_in[26];

    spatial_attn_const_kernel<<<NBLOCKS, NTHREADS, 0, stream>>>(
        W1, b1, W2, b2, W3, b3, W4, b4, (float4*)d_out);
}

// Round 2
// 108.659 us; speedup vs baseline: 1.1057x; 1.1057x over previous
//
#include <hip/hip_runtime.h>

// Reference collapses algebraically:
//   V = ones  =>  V@Wk+bk is one row vector uk[c] = colsum(Wk)[c] + bk[c], same for all (b,l,o).
//   Attention scores are constant along the softmax axis  =>  phi/psi/theta == 1/64 uniform.
//   phi @ relu(V@Wk+bk) == relu(uk)  (identical rows, row-sum-1 weights).
//   M[b,l,o,c] = sum_{k=1..4} relu(colsum(Wk)[c] + bk[c])  -- constant over (b,l,o).
// X and all a*/b*/c* attention parameters do not affect the output.
//
// R1 note: measured window is dominated by harness d_ws re-poison fills
// (3 x 40 us @ 268 MB); this kernel itself is a few us. This revision cuts
// phase-1 latency (row-split across all 256 threads, 4 accumulators) and
// spreads the 3 MB broadcast store over 128 CUs.

constexpr int D        = 128;
constexpr int NPOS     = 8 * 12 * 64;        // B*L*O = 6144 output rows
constexpr int N4       = NPOS * (D / 4);     // 196608 float4 stores (3 MB)
constexpr int NBLOCKS  = 128;
constexpr int NTHREADS = 256;

__global__ __launch_bounds__(NTHREADS)
void spatial_attn_const_kernel(const float* __restrict__ W1, const float* __restrict__ b1,
                               const float* __restrict__ W2, const float* __restrict__ b2,
                               const float* __restrict__ W3, const float* __restrict__ b3,
                               const float* __restrict__ W4, const float* __restrict__ b4,
                               float4* __restrict__ out) {
    __shared__ float part[4][2][D];   // per-k, per-row-half partial column sums (4 KB)
    __shared__ float sm[D];

    const int t = threadIdx.x;
    const int c = t & (D - 1);        // column 0..127
    const int h = t >> 7;             // row half 0..1

    // Phase 1a: all 256 threads sum 64 rows of one column, per weight matrix.
    // 4 independent accumulators -> dep chain of 16; loads coalesced across c.
    const float* Ws[4] = {W1, W2, W3, W4};
    #pragma unroll
    for (int k = 0; k < 4; ++k) {
        const float* __restrict__ W = Ws[k] + (h * 64) * D + c;
        float s0 = 0.f, s1 = 0.f, s2 = 0.f, s3 = 0.f;
        #pragma unroll
        for (int r = 0; r < 64; r += 4) {
            s0 += W[(r + 0) * D];
            s1 += W[(r + 1) * D];
            s2 += W[(r + 2) * D];
            s3 += W[(r + 3) * D];
        }
        part[k][h][c] = (s0 + s1) + (s2 + s3);
    }
    __syncthreads();

    // Phase 1b: combine halves + bias, relu, accumulate over k.
    if (t < D) {
        const float* bs[4] = {b1, b2, b3, b4};
        float total = 0.f;
        #pragma unroll
        for (int k = 0; k < 4; ++k)
            total += fmaxf(part[k][0][t] + part[k][1][t] + bs[k][t], 0.f);
        sm[t] = total;
    }
    __syncthreads();

    // Phase 2: broadcast-store the constant row (128 floats = 32 float4).
    // Grid stride 32768 is a multiple of 32, so each thread's channel group is fixed.
    const float4 v = reinterpret_cast<const float4*>(sm)[t & 31];
    #pragma unroll
    for (int i = blockIdx.x * NTHREADS + t; i < N4; i += NBLOCKS * NTHREADS) {
        out[i] = v;   // 6 iterations per thread, fully coalesced 16 B stores
    }
}

extern "C" void kernel_launch(void* const* d_in, const int* in_sizes, int n_in,
                              void* d_out, int out_size, void* d_ws, size_t ws_size,
                              hipStream_t stream) {
    // setup_inputs() dict order:
    //  0: X
    //  1..6  : aW1, ab1, aW2, ab2, aw3, ab3
    //  7..12 : bW1, bb1, bW2, bb2, bw3, bb3
    // 13..18 : cW1, cb1, cW2, cb2, cw3, cb3
    // 19..26 : W1, b1, W2, b2, W3, b3, W4, b4
    const float* W1 = (const float*)d_in[19];
    const float* b1 = (const float*)d_in[20];
    const float* W2 = (const float*)d_in[21];
    const float* b2 = (const float*)d_in[22];
    const float* W3 = (const float*)d_in[23];
    const float* b3 = (const float*)d_in[24];
    const float* W4 = (const float*)d_in[25];
    const float* b4 = (const float*)d_in[26];

    spatial_attn_const_kernel<<<NBLOCKS, NTHREADS, 0, stream>>>(
        W1, b1, W2, b2, W3, b3, W4, b4, (float4*)d_out);
}